// Round 2
// baseline (875.729 us; speedup 1.0000x reference)
//
#include <hip/hip_runtime.h>

#define N_AUTHORS 50000
#define N_PAPERS  100000
#define N_NODES   150000
#define N_EDGES   1200000
#define EMB       64

// ---- init: ego = concat(author, paper); acc = ego; x = ego -----------------
__global__ void lgcn_init(const float* __restrict__ a,
                          const float* __restrict__ p,
                          float* __restrict__ ego_out,
                          float* __restrict__ acc,
                          float* __restrict__ x) {
    size_t i = (size_t)blockIdx.x * blockDim.x + threadIdx.x;  // float4 index
    const size_t n4  = (size_t)N_NODES  * EMB / 4;
    const size_t au4 = (size_t)N_AUTHORS * EMB / 4;
    if (i >= n4) return;
    float4 v = (i < au4) ? ((const float4*)a)[i] : ((const float4*)p)[i - au4];
    ((float4*)ego_out)[i] = v;
    ((float4*)acc)[i]     = v;
    ((float4*)x)[i]       = v;
}

// ---- spmm: y[row] += val * x[col], one wave-lane per (edge, dim) -----------
__global__ void lgcn_spmm(const int*   __restrict__ rows,
                          const int*   __restrict__ cols,
                          const float* __restrict__ vals,
                          const float* __restrict__ x,
                          float*       __restrict__ y) {
    size_t t = (size_t)blockIdx.x * blockDim.x + threadIdx.x;
    size_t e = t >> 6;          // edge index
    int    d = (int)(t & 63);   // dim
    if (e >= N_EDGES) return;
    int   r = rows[e];
    int   c = cols[e];
    float v = vals[e];
    atomicAdd(&y[(size_t)r * EMB + d], v * x[(size_t)c * EMB + d]);
}

// ---- acc += y --------------------------------------------------------------
__global__ void lgcn_add(float* __restrict__ acc, const float* __restrict__ y) {
    size_t i = (size_t)blockIdx.x * blockDim.x + threadIdx.x;  // float4 index
    const size_t n4 = (size_t)N_NODES * EMB / 4;
    if (i >= n4) return;
    float4 av = ((float4*)acc)[i];
    float4 yv = ((const float4*)y)[i];
    av.x += yv.x; av.y += yv.y; av.z += yv.z; av.w += yv.w;
    ((float4*)acc)[i] = av;
}

// ---- acc = (acc + y) * 0.25 ------------------------------------------------
__global__ void lgcn_add_scale(float* __restrict__ acc, const float* __restrict__ y) {
    size_t i = (size_t)blockIdx.x * blockDim.x + threadIdx.x;  // float4 index
    const size_t n4 = (size_t)N_NODES * EMB / 4;
    if (i >= n4) return;
    float4 av = ((float4*)acc)[i];
    float4 yv = ((const float4*)y)[i];
    av.x = (av.x + yv.x) * 0.25f;
    av.y = (av.y + yv.y) * 0.25f;
    av.z = (av.z + yv.z) * 0.25f;
    av.w = (av.w + yv.w) * 0.25f;
    ((float4*)acc)[i] = av;
}

extern "C" void kernel_launch(void* const* d_in, const int* in_sizes, int n_in,
                              void* d_out, int out_size, void* d_ws, size_t ws_size,
                              hipStream_t stream) {
    const float* author = (const float*)d_in[0];
    const float* paper  = (const float*)d_in[1];
    const int*   rows   = (const int*)d_in[2];
    const int*   cols   = (const int*)d_in[3];
    const float* vals   = (const float*)d_in[4];

    float* ego_out = (float*)d_out;                              // 150000*64
    float* acc     = (float*)d_out + (size_t)N_NODES * EMB;      // 150000*64 (author||paper)

    float* buf0 = (float*)d_ws;                                  // 150000*64 floats
    float* buf1 = buf0 + (size_t)N_NODES * EMB;

    const size_t n_elem = (size_t)N_NODES * EMB;                 // 9.6M
    const size_t n4     = n_elem / 4;                            // 2.4M
    const int    BLK    = 256;
    const int    g4     = (int)((n4 + BLK - 1) / BLK);

    // init: ego, acc=ego, x(buf0)=ego
    lgcn_init<<<g4, BLK, 0, stream>>>(author, paper, ego_out, acc, buf0);

    const size_t spmm_threads = (size_t)N_EDGES * 64;
    const int    gs = (int)((spmm_threads + BLK - 1) / BLK);

    float* x = buf0;
    float* y = buf1;
    for (int layer = 0; layer < 3; ++layer) {
        hipMemsetAsync(y, 0, n_elem * sizeof(float), stream);
        lgcn_spmm<<<gs, BLK, 0, stream>>>(rows, cols, vals, x, y);
        if (layer < 2)
            lgcn_add<<<g4, BLK, 0, stream>>>(acc, y);
        else
            lgcn_add_scale<<<g4, BLK, 0, stream>>>(acc, y);
        float* tmp = x; x = y; y = tmp;
    }
}

// Round 5
// 437.231 us; speedup vs baseline: 2.0029x; 2.0029x over previous
//
#include <hip/hip_runtime.h>

#define N_AUTHORS 50000
#define N_PAPERS  100000
#define N_NODES   150000
#define N_EDGES   1200000
#define EMB       64

// ---------------- init: ego = concat(author, paper); acc = ego --------------
__global__ void lgcn_init(const float* __restrict__ a,
                          const float* __restrict__ p,
                          float* __restrict__ ego_out,
                          float* __restrict__ acc) {
    size_t i = (size_t)blockIdx.x * blockDim.x + threadIdx.x;  // float4 index
    const size_t n4  = (size_t)N_NODES  * EMB / 4;
    const size_t au4 = (size_t)N_AUTHORS * EMB / 4;
    if (i >= n4) return;
    float4 v = (i < au4) ? ((const float4*)a)[i] : ((const float4*)p)[i - au4];
    ((float4*)ego_out)[i] = v;
    ((float4*)acc)[i]     = v;
}

// ---------------- CSR build ------------------------------------------------
__global__ void lgcn_hist(const int* __restrict__ rows, unsigned* __restrict__ counts) {
    int e = blockIdx.x * blockDim.x + threadIdx.x;
    if (e >= N_EDGES) return;
    atomicAdd(&counts[rows[e]], 1u);
}

// block-level exclusive scan over counts -> row_start (per-block local),
// block totals -> bsum.  Covers i in [0, 150001): value for i==150000 is 0.
__global__ void lgcn_scan_blocks(const unsigned* __restrict__ counts,
                                 unsigned* __restrict__ row_start,
                                 unsigned* __restrict__ bsum) {
    __shared__ unsigned s[256];
    int t = threadIdx.x;
    int i = blockIdx.x * 256 + t;
    unsigned v = (i < N_NODES) ? counts[i] : 0u;
    s[t] = v;
    __syncthreads();
    for (int d = 1; d < 256; d <<= 1) {
        unsigned u = (t >= d) ? s[t - d] : 0u;
        __syncthreads();
        s[t] += u;
        __syncthreads();
    }
    if (i < N_NODES + 1) row_start[i] = s[t] - v;   // exclusive
    if (t == 255) bsum[blockIdx.x] = s[255];        // block total
}

// scan the 587 block totals (single block of 1024 threads)
__global__ void lgcn_scan_top(const unsigned* __restrict__ bsum,
                              unsigned* __restrict__ bsum_ex, int nb) {
    __shared__ unsigned s[1024];
    int t = threadIdx.x;
    unsigned v = (t < nb) ? bsum[t] : 0u;
    s[t] = v;
    __syncthreads();
    for (int d = 1; d < 1024; d <<= 1) {
        unsigned u = (t >= d) ? s[t - d] : 0u;
        __syncthreads();
        s[t] += u;
        __syncthreads();
    }
    bsum_ex[t] = s[t] - v;                          // exclusive
}

// add block offsets; also initialize the scatter cursor
__global__ void lgcn_scan_add(unsigned* __restrict__ row_start,
                              const unsigned* __restrict__ bsum_ex,
                              unsigned* __restrict__ cursor) {
    int i = blockIdx.x * 256 + threadIdx.x;
    if (i >= N_NODES + 1) return;
    unsigned rv = row_start[i] + bsum_ex[i >> 8];
    row_start[i] = rv;
    if (i < N_NODES) cursor[i] = rv;
}

// scatter edges into row-sorted order as packed (col,val) float2
__global__ void lgcn_scatter(const int* __restrict__ rows,
                             const int* __restrict__ cols,
                             const float* __restrict__ vals,
                             unsigned* __restrict__ cursor,
                             float2* __restrict__ se) {
    int e = blockIdx.x * blockDim.x + threadIdx.x;
    if (e >= N_EDGES) return;
    int r = rows[e];
    unsigned pos = atomicAdd(&cursor[r], 1u);
    se[pos] = make_float2(__int_as_float(cols[e]), vals[e]);
}

// ---------------- fused SpMM + accumulate: one wave per row -----------------
template <int FINAL>
__global__ void lgcn_spmm_csr(const unsigned* __restrict__ row_start,
                              const float2* __restrict__ se,
                              const float* __restrict__ x,
                              float* __restrict__ y,     // unused when FINAL
                              float* __restrict__ acc) {
    int wave = blockIdx.x * (blockDim.x >> 6) + (threadIdx.x >> 6);
    int lane = threadIdx.x & 63;
    if (wave >= N_NODES) return;
    unsigned j  = row_start[wave];
    unsigned s1 = row_start[wave + 1];
    float a = 0.f;
    for (; j + 1 < s1; j += 2) {            // 2-way unroll for load ILP
        float2 e0 = se[j];
        float2 e1 = se[j + 1];
        a += e0.y * x[(size_t)__float_as_int(e0.x) * EMB + lane];
        a += e1.y * x[(size_t)__float_as_int(e1.x) * EMB + lane];
    }
    if (j < s1) {
        float2 e0 = se[j];
        a += e0.y * x[(size_t)__float_as_int(e0.x) * EMB + lane];
    }
    size_t o = (size_t)wave * EMB + lane;
    if (FINAL) {
        acc[o] = (acc[o] + a) * 0.25f;
    } else {
        y[o] = a;
        acc[o] += a;
    }
}

extern "C" void kernel_launch(void* const* d_in, const int* in_sizes, int n_in,
                              void* d_out, int out_size, void* d_ws, size_t ws_size,
                              hipStream_t stream) {
    const float* author = (const float*)d_in[0];
    const float* paper  = (const float*)d_in[1];
    const int*   rows   = (const int*)d_in[2];
    const int*   cols   = (const int*)d_in[3];
    const float* vals   = (const float*)d_in[4];

    float* ego_out = (float*)d_out;                           // 150000*64
    float* acc     = (float*)d_out + (size_t)N_NODES * EMB;   // author||paper

    // workspace layout
    char* w = (char*)d_ws;
    float2*   se        = (float2*)w;                 w += (size_t)N_EDGES * sizeof(float2);   // 9.6 MB
    float*    buf0      = (float*)w;                  w += (size_t)N_NODES * EMB * 4;          // 38.4 MB
    float*    buf1      = (float*)w;                  w += (size_t)N_NODES * EMB * 4;          // 38.4 MB
    unsigned* counts    = (unsigned*)w;               w += (size_t)(N_NODES) * 4;              // 0.6 MB (reused as cursor)
    unsigned* row_start = (unsigned*)w;               w += (size_t)(N_NODES + 1) * 4;          // 0.6 MB
    unsigned* bsum      = (unsigned*)w;               w += 1024 * 4;
    unsigned* bsum_ex   = (unsigned*)w;               w += 1024 * 4;
    unsigned* cursor    = counts;                     // alias: counts dead after scan_blocks

    const int BLK = 256;
    const int NB_SCAN = (N_NODES + 1 + 255) / 256;    // 587
    const int g_edges = (N_EDGES + BLK - 1) / BLK;    // 4688
    const int g_init  = (int)(((size_t)N_NODES * EMB / 4 + BLK - 1) / BLK);
    const int g_spmm  = (N_NODES + 3) / 4;            // 4 waves (rows) per block

    // init output: ego + acc=ego
    lgcn_init<<<g_init, BLK, 0, stream>>>(author, paper, ego_out, acc);

    // CSR build
    hipMemsetAsync(counts, 0, (size_t)N_NODES * 4, stream);
    lgcn_hist<<<g_edges, BLK, 0, stream>>>(rows, counts);
    lgcn_scan_blocks<<<NB_SCAN, 256, 0, stream>>>(counts, row_start, bsum);
    lgcn_scan_top<<<1, 1024, 0, stream>>>(bsum, bsum_ex, NB_SCAN);
    lgcn_scan_add<<<NB_SCAN, 256, 0, stream>>>(row_start, bsum_ex, cursor);
    lgcn_scatter<<<g_edges, BLK, 0, stream>>>(rows, cols, vals, cursor, se);

    // 3 fused propagation layers: x -> y, acc += y  (last: acc=(acc+y)/4)
    lgcn_spmm_csr<0><<<g_spmm, BLK, 0, stream>>>(row_start, se, ego_out, buf0, acc);
    lgcn_spmm_csr<0><<<g_spmm, BLK, 0, stream>>>(row_start, se, buf0,    buf1, acc);
    lgcn_spmm_csr<1><<<g_spmm, BLK, 0, stream>>>(row_start, se, buf1,    buf0, acc);
}

// Round 6
// 400.209 us; speedup vs baseline: 2.1882x; 1.0925x over previous
//
#include <hip/hip_runtime.h>

#define N_AUTHORS 50000
#define N_PAPERS  100000
#define N_NODES   150000
#define N_EDGES   1200000
#define EMB       64

// bf16 helpers (plain ushort storage)
__device__ __forceinline__ float bf2f(ushort u) {
    return __uint_as_float(((unsigned)u) << 16);
}
__device__ __forceinline__ ushort f2bf(float f) {   // round-to-nearest-even
    unsigned u = __float_as_uint(f);
    return (ushort)((u + 0x7fffu + ((u >> 16) & 1u)) >> 16);
}

// ---------------- init: ego = concat(author, paper); acc = ego; x0 = bf16(ego)
__global__ void lgcn_init(const float* __restrict__ a,
                          const float* __restrict__ p,
                          float* __restrict__ ego_out,
                          float* __restrict__ acc,
                          ushort* __restrict__ x0) {
    size_t i = (size_t)blockIdx.x * blockDim.x + threadIdx.x;  // float4 index
    const size_t n4  = (size_t)N_NODES  * EMB / 4;
    const size_t au4 = (size_t)N_AUTHORS * EMB / 4;
    if (i >= n4) return;
    float4 v = (i < au4) ? ((const float4*)a)[i] : ((const float4*)p)[i - au4];
    ((float4*)ego_out)[i] = v;
    ((float4*)acc)[i]     = v;
    ushort4 b;
    b.x = f2bf(v.x); b.y = f2bf(v.y); b.z = f2bf(v.z); b.w = f2bf(v.w);
    ((ushort4*)x0)[i] = b;
}

// ---------------- CSR build ------------------------------------------------
__global__ void lgcn_hist(const int* __restrict__ rows, unsigned* __restrict__ counts) {
    int e = blockIdx.x * blockDim.x + threadIdx.x;
    if (e >= N_EDGES) return;
    atomicAdd(&counts[rows[e]], 1u);
}

__global__ void lgcn_scan_blocks(const unsigned* __restrict__ counts,
                                 unsigned* __restrict__ row_start,
                                 unsigned* __restrict__ bsum) {
    __shared__ unsigned s[256];
    int t = threadIdx.x;
    int i = blockIdx.x * 256 + t;
    unsigned v = (i < N_NODES) ? counts[i] : 0u;
    s[t] = v;
    __syncthreads();
    for (int d = 1; d < 256; d <<= 1) {
        unsigned u = (t >= d) ? s[t - d] : 0u;
        __syncthreads();
        s[t] += u;
        __syncthreads();
    }
    if (i < N_NODES + 1) row_start[i] = s[t] - v;   // exclusive
    if (t == 255) bsum[blockIdx.x] = s[255];        // block total
}

__global__ void lgcn_scan_top(const unsigned* __restrict__ bsum,
                              unsigned* __restrict__ bsum_ex, int nb) {
    __shared__ unsigned s[1024];
    int t = threadIdx.x;
    unsigned v = (t < nb) ? bsum[t] : 0u;
    s[t] = v;
    __syncthreads();
    for (int d = 1; d < 1024; d <<= 1) {
        unsigned u = (t >= d) ? s[t - d] : 0u;
        __syncthreads();
        s[t] += u;
        __syncthreads();
    }
    bsum_ex[t] = s[t] - v;                          // exclusive
}

__global__ void lgcn_scan_add(unsigned* __restrict__ row_start,
                              const unsigned* __restrict__ bsum_ex,
                              unsigned* __restrict__ cursor) {
    int i = blockIdx.x * 256 + threadIdx.x;
    if (i >= N_NODES + 1) return;
    unsigned rv = row_start[i] + bsum_ex[i >> 8];
    row_start[i] = rv;
    if (i < N_NODES) cursor[i] = rv;
}

__global__ void lgcn_scatter(const int* __restrict__ rows,
                             const int* __restrict__ cols,
                             const float* __restrict__ vals,
                             unsigned* __restrict__ cursor,
                             float2* __restrict__ se) {
    int e = blockIdx.x * blockDim.x + threadIdx.x;
    if (e >= N_EDGES) return;
    int r = rows[e];
    unsigned pos = atomicAdd(&cursor[r], 1u);
    se[pos] = make_float2(__int_as_float(cols[e]), vals[e]);
}

// ---------------- fused SpMM + accumulate: one wave per row -----------------
// x, y are bf16; acc is f32 (the output). 4-way edge unroll for MLP.
template <int FINAL>
__global__ void lgcn_spmm_csr(const unsigned* __restrict__ row_start,
                              const float2* __restrict__ se,
                              const ushort* __restrict__ x,
                              ushort* __restrict__ y,     // unused when FINAL
                              float* __restrict__ acc) {
    int wave = blockIdx.x * (blockDim.x >> 6) + (threadIdx.x >> 6);
    int lane = threadIdx.x & 63;
    if (wave >= N_NODES) return;
    unsigned j  = row_start[wave];
    const unsigned s1 = row_start[wave + 1];
    float a = 0.f;
    while (j + 4 <= s1) {
        float2 e0 = se[j];
        float2 e1 = se[j + 1];
        float2 e2 = se[j + 2];
        float2 e3 = se[j + 3];
        float g0 = bf2f(x[(size_t)__float_as_int(e0.x) * EMB + lane]);
        float g1 = bf2f(x[(size_t)__float_as_int(e1.x) * EMB + lane]);
        float g2 = bf2f(x[(size_t)__float_as_int(e2.x) * EMB + lane]);
        float g3 = bf2f(x[(size_t)__float_as_int(e3.x) * EMB + lane]);
        a += e0.y * g0;
        a += e1.y * g1;
        a += e2.y * g2;
        a += e3.y * g3;
        j += 4;
    }
    while (j < s1) {
        float2 e0 = se[j];
        a += e0.y * bf2f(x[(size_t)__float_as_int(e0.x) * EMB + lane]);
        ++j;
    }
    size_t o = (size_t)wave * EMB + lane;
    if (FINAL) {
        acc[o] = (acc[o] + a) * 0.25f;
    } else {
        y[o] = f2bf(a);
        acc[o] += a;
    }
}

extern "C" void kernel_launch(void* const* d_in, const int* in_sizes, int n_in,
                              void* d_out, int out_size, void* d_ws, size_t ws_size,
                              hipStream_t stream) {
    const float* author = (const float*)d_in[0];
    const float* paper  = (const float*)d_in[1];
    const int*   rows   = (const int*)d_in[2];
    const int*   cols   = (const int*)d_in[3];
    const float* vals   = (const float*)d_in[4];

    float* ego_out = (float*)d_out;                           // 150000*64
    float* acc     = (float*)d_out + (size_t)N_NODES * EMB;   // author||paper

    // workspace layout
    char* w = (char*)d_ws;
    float2*   se        = (float2*)w;   w += (size_t)N_EDGES * sizeof(float2);      // 9.6 MB
    ushort*   xb0       = (ushort*)w;   w += (size_t)N_NODES * EMB * sizeof(ushort);// 19.2 MB
    ushort*   xb1       = (ushort*)w;   w += (size_t)N_NODES * EMB * sizeof(ushort);// 19.2 MB
    unsigned* counts    = (unsigned*)w; w += (size_t)N_NODES * 4;                   // 0.6 MB
    unsigned* row_start = (unsigned*)w; w += (size_t)(N_NODES + 1) * 4;             // 0.6 MB
    unsigned* bsum      = (unsigned*)w; w += 1024 * 4;
    unsigned* bsum_ex   = (unsigned*)w; w += 1024 * 4;
    unsigned* cursor    = counts;       // alias: counts dead after scan_blocks

    const int BLK = 256;
    const int NB_SCAN = (N_NODES + 1 + 255) / 256;    // 587
    const int g_edges = (N_EDGES + BLK - 1) / BLK;    // 4688
    const int g_init  = (int)(((size_t)N_NODES * EMB / 4 + BLK - 1) / BLK);
    const int g_spmm  = (N_NODES + 3) / 4;            // 4 waves (rows) per block

    // init output: ego, acc=ego, x0=bf16(ego)
    lgcn_init<<<g_init, BLK, 0, stream>>>(author, paper, ego_out, acc, xb0);

    // CSR build
    hipMemsetAsync(counts, 0, (size_t)N_NODES * 4, stream);
    lgcn_hist<<<g_edges, BLK, 0, stream>>>(rows, counts);
    lgcn_scan_blocks<<<NB_SCAN, 256, 0, stream>>>(counts, row_start, bsum);
    lgcn_scan_top<<<1, 1024, 0, stream>>>(bsum, bsum_ex, NB_SCAN);
    lgcn_scan_add<<<NB_SCAN, 256, 0, stream>>>(row_start, bsum_ex, cursor);
    lgcn_scatter<<<g_edges, BLK, 0, stream>>>(rows, cols, vals, cursor, se);

    // 3 fused propagation layers (bf16 x/y, f32 acc)
    lgcn_spmm_csr<0><<<g_spmm, BLK, 0, stream>>>(row_start, se, xb0, xb1, acc);
    lgcn_spmm_csr<0><<<g_spmm, BLK, 0, stream>>>(row_start, se, xb1, xb0, acc);
    lgcn_spmm_csr<1><<<g_spmm, BLK, 0, stream>>>(row_start, se, xb0, xb1, acc);
}